// Round 16
// baseline (83.118 us; speedup 1.0000x reference)
//
#include <hip/hip_runtime.h>

// Problem constants
#define NBATCH 8
#define TSEQ 2048
#define EDIM 1024
#define HDIM 64
#define NROW (NBATCH * TSEQ)  // 16384

typedef unsigned short u16;
typedef __attribute__((ext_vector_type(8))) short bf16x8;   // 8 bf16 (4 VGPRs)
typedef __attribute__((ext_vector_type(8))) short short8;   // 16B load vehicle
typedef __attribute__((ext_vector_type(4))) float f32x4;

typedef unsigned int uint_as1 __attribute__((address_space(1)));
typedef unsigned int uint_as3 __attribute__((address_space(3)));

// fp32 -> bf16 round-to-nearest-even (bit pattern)
__device__ __forceinline__ u16 f2b(float x) {
  unsigned int u = __float_as_uint(x);
  unsigned int r = (u + 0x7fffu + ((u >> 16) & 1u)) >> 16;
  return (u16)r;
}
__device__ __forceinline__ float b2f(u16 h) {
  return __uint_as_float(((unsigned int)h) << 16);
}
// async global->LDS, 16 B per lane (dest = wave base + lane*16, linear)
__device__ __forceinline__ void gl16(const void* g, void* l) {
  __builtin_amdgcn_global_load_lds((const uint_as1*)g, (uint_as3*)l, 16, 0, 0);
}

// ---------------------------------------------------------------------------
// Kernel 0: W [1024][64] fp32 -> Wt [192][1024] bf16 (transposed), via LDS.
// ---------------------------------------------------------------------------
__global__ __launch_bounds__(256) void wt_kernel(
    const float* __restrict__ Wq, const float* __restrict__ Wk,
    const float* __restrict__ Wv, u16* __restrict__ Wt) {
  __shared__ float s[64][65];
  const int o = blockIdx.x >> 4, et = blockIdx.x & 15;
  const float* W = (o == 0) ? Wq : (o == 1) ? Wk : Wv;
  const int t = threadIdx.x;
  const int e0 = et * 64;
#pragma unroll
  for (int i = 0; i < 16; i++) {
    int e = i * 4 + (t >> 6), h = t & 63;
    s[e][h] = W[(size_t)(e0 + e) * HDIM + h];
  }
  __syncthreads();
#pragma unroll
  for (int j = 0; j < 16; j++) {
    int h = j * 4 + (t >> 6), e = t & 63;
    Wt[(size_t)(o * 64 + h) * EDIM + e0 + e] = f2b(s[e][h]);
  }
}

// ---------------------------------------------------------------------------
// Kernel 1: QKV projection, r16: o-SPLIT for TLP (the one axis never
// isolated — every prior proj ran 2 blocks/CU; this runs 5-6).
// Grid 1536 = 512 t-tiles x 3 outputs (o = bid%3 fastest -> the 3 siblings
// sharing an X tile are temporally close; X re-reads L3-absorbed).
// Block = 32t x 64h (one of Q/K/V); wave w owns h-rows w*16..+15 (1 C-tile
// x 2 colsets). BK=64, 16 stages, r9's exact counted-vmcnt dbuf skeleton:
// per thread per stage 4 gl16 (2 X + 2 W) -> vmcnt(4) waits only stage k
// while k+1's 4 stay in flight. LDS 2x(8K X + 8K W) = 32 KB.
// W L2 traffic unchanged vs r9 (each block stages only its 64-row o-slice).
// ---------------------------------------------------------------------------
#define XBUF (32 * 256)   // 8 KB per buffer (32 t x 16 gran fp32)
#define WBUF (64 * 128)   // 8 KB per buffer (64 h x 8 gran bf16)

__global__ __launch_bounds__(256, 4) void proj_mfma(
    const float* __restrict__ X, const u16* __restrict__ Wt,
    const float* __restrict__ bq, const float* __restrict__ bk,
    const float* __restrict__ bv,
    u16* __restrict__ Qb, u16* __restrict__ Kb, u16* __restrict__ Vt) {
  __shared__ __align__(16) char sx[2 * XBUF];
  __shared__ __align__(16) char sw[2 * WBUF];

  const int tid = threadIdx.x;
  const int w = tid >> 6, l = tid & 63;
  const int g = l >> 4, li = l & 15;
  const int o = blockIdx.x % 3;              // 0=Q 1=K 2=V
  const long bt0 = (long)(blockIdx.x / 3) * 32;

  const int xr = tid >> 4, xc = tid & 15;
  const float* xsrc0 = X + (bt0 + xr) * EDIM + ((xc ^ (xr & 7)) * 4);
  const float* xsrc1 = X + (bt0 + 16 + xr) * EDIM + ((xc ^ (xr & 7)) * 4);
  const u16* wsrc = Wt + (size_t)o * 64 * EDIM;

  f32x4 acc[2];  // [cs]
  acc[0] = (f32x4)0.f;
  acc[1] = (f32x4)0.f;

  // 4 gl16 per thread per stage (2 X + 2 W) -> vmcnt counting unit
#define STAGE(BUF, E0)                                                       \
  do {                                                                       \
    gl16(xsrc0 + (E0), sx + (BUF)*XBUF + tid * 16);                          \
    gl16(xsrc1 + (E0), sx + (BUF)*XBUF + (tid + 256) * 16);                  \
    _Pragma("unroll") for (int j = 0; j < 2; j++) {                          \
      const int L = j * 256 + tid;                                           \
      const int r = L >> 3, c = L & 7;                                       \
      gl16(wsrc + (size_t)r * EDIM + (E0) + ((c ^ (r & 7)) * 8),             \
           sw + (BUF)*WBUF + L * 16);                                        \
    }                                                                        \
  } while (0)

  STAGE(0, 0);
  asm volatile("s_waitcnt vmcnt(0)" ::: "memory");
  __builtin_amdgcn_sched_barrier(0);
  __builtin_amdgcn_s_barrier();
  __builtin_amdgcn_sched_barrier(0);

  for (int ks = 0; ks < 16; ks++) {
    const int buf = ks & 1;
    if (ks < 15) STAGE(buf ^ 1, (ks + 1) * 64);
    __builtin_amdgcn_sched_barrier(0);
    if (ks < 15) {
      asm volatile("s_waitcnt vmcnt(4)" ::: "memory");
    } else {
      asm volatile("s_waitcnt vmcnt(0)" ::: "memory");
    }
    __builtin_amdgcn_sched_barrier(0);
    __builtin_amdgcn_s_barrier();  // all waves' stage-k data in LDS
    __builtin_amdgcn_sched_barrier(0);

    const char* xb = sx + buf * XBUF;
    const char* wb = sw + buf * WBUF;
    bf16x8 bfr[2][2];
#pragma unroll
    for (int cs = 0; cs < 2; cs++) {
      const int row = cs * 16 + li;
#pragma unroll
      for (int kc = 0; kc < 2; kc++) {
        const int G0 = kc * 8 + g * 2;
        const float4 f0 = *(const float4*)(xb + row * 256 + ((G0 ^ (row & 7)) * 16));
        const float4 f1 = *(const float4*)(xb + row * 256 + (((G0 + 1) ^ (row & 7)) * 16));
        bfr[cs][kc] = (bf16x8){(short)f2b(f0.x), (short)f2b(f0.y),
                               (short)f2b(f0.z), (short)f2b(f0.w),
                               (short)f2b(f1.x), (short)f2b(f1.y),
                               (short)f2b(f1.z), (short)f2b(f1.w)};
      }
    }
    {
      const int row = w * 16 + li;
#pragma unroll
      for (int kc = 0; kc < 2; kc++) {
        const int G = kc * 4 + g;
        const bf16x8 af = *(const bf16x8*)(wb + row * 128 + ((G ^ (row & 7)) * 16));
        acc[0] = __builtin_amdgcn_mfma_f32_16x16x32_bf16(af, bfr[0][kc], acc[0], 0, 0, 0);
        acc[1] = __builtin_amdgcn_mfma_f32_16x16x32_bf16(af, bfr[1][kc], acc[1], 0, 0, 0);
      }
    }
    __builtin_amdgcn_sched_barrier(0);
    __builtin_amdgcn_s_barrier();  // reads of buf done before next overwrite
    __builtin_amdgcn_sched_barrier(0);
  }
#undef STAGE

  // epilogue: lane holds out^T[h0 = w*16+g*4 (+r)][t = bt0+cs*16+li]
  const float qscale = 0.18033688011112042f;  // 0.125 * log2(e)
  const int h0 = w * 16 + g * 4;
  const float* bias = (o == 0) ? bq : (o == 1) ? bk : bv;
  const float4 bb = *(const float4*)&bias[h0];
#pragma unroll
  for (int cs = 0; cs < 2; cs++) {
    const long tg = bt0 + cs * 16 + li;
    const int b = (int)(tg >> 11), tl = (int)(tg & 2047);
    const f32x4 a = acc[cs];
    float v0 = a.x + bb.x, v1 = a.y + bb.y;
    float v2 = a.z + bb.z, v3 = a.w + bb.w;
    if (o == 0) {
      v0 *= qscale; v1 *= qscale; v2 *= qscale; v3 *= qscale;
      uint2 pk = make_uint2((unsigned)f2b(v0) | ((unsigned)f2b(v1) << 16),
                            (unsigned)f2b(v2) | ((unsigned)f2b(v3) << 16));
      *(uint2*)&Qb[tg * HDIM + h0] = pk;
    } else if (o == 1) {
      uint2 pk = make_uint2((unsigned)f2b(v0) | ((unsigned)f2b(v1) << 16),
                            (unsigned)f2b(v2) | ((unsigned)f2b(v3) << 16));
      *(uint2*)&Kb[tg * HDIM + h0] = pk;
    } else {
      Vt[(size_t)(b * 64 + h0 + 0) * TSEQ + tl] = f2b(v0);
      Vt[(size_t)(b * 64 + h0 + 1) * TSEQ + tl] = f2b(v1);
      Vt[(size_t)(b * 64 + h0 + 2) * TSEQ + tl] = f2b(v2);
      Vt[(size_t)(b * 64 + h0 + 3) * TSEQ + tl] = f2b(v3);
    }
  }
}

// ---------------------------------------------------------------------------
// Kernel 2: per-64-chunk V sums + suffix table (single kernel).
// CSS[b][c][h] = sum_{k >= c*64} V[b][k][h], c = 0..32 (CSS[32] = 0).
// ---------------------------------------------------------------------------
__global__ __launch_bounds__(1024) void css_kernel(const u16* __restrict__ Vt,
                                                   float* __restrict__ CSS) {
  __shared__ float cs[32][64];
  const int b = blockIdx.x;
  const int t = threadIdx.x;
  const int h = t & 63, cg = t >> 6;
  const u16* vp = Vt + ((size_t)b * 64 + h) * TSEQ + cg * 128;
  float s0 = 0.f, s1 = 0.f;
#pragma unroll
  for (int i = 0; i < 8; i++) {
    const short8 a = *(const short8*)(vp + i * 8);
    s0 += b2f((u16)a[0]) + b2f((u16)a[1]) + b2f((u16)a[2]) + b2f((u16)a[3]) +
          b2f((u16)a[4]) + b2f((u16)a[5]) + b2f((u16)a[6]) + b2f((u16)a[7]);
  }
#pragma unroll
  for (int i = 8; i < 16; i++) {
    const short8 a = *(const short8*)(vp + i * 8);
    s1 += b2f((u16)a[0]) + b2f((u16)a[1]) + b2f((u16)a[2]) + b2f((u16)a[3]) +
          b2f((u16)a[4]) + b2f((u16)a[5]) + b2f((u16)a[6]) + b2f((u16)a[7]);
  }
  cs[cg * 2 + 0][h] = s0;
  cs[cg * 2 + 1][h] = s1;
  __syncthreads();
  if (t < 64) {
    float S = 0.f;
    CSS[((size_t)b * 33 + 32) * 64 + t] = 0.f;
    for (int c = 31; c >= 0; c--) {
      S += cs[c][t];
      CSS[((size_t)b * 33 + c) * 64 + t] = S;
    }
  }
}

// ---------------------------------------------------------------------------
// Kernel 3: MFMA attention: swapped QK^T, 32 q-rows/block, s_setprio around
// MFMA clusters (best measured attn variant; unchanged).
// ---------------------------------------------------------------------------
#define ISSUE_K(K0A, K1A, KO)                                              \
  do {                                                                     \
    _Pragma("unroll") for (int n = 0; n < 4; n++) {                        \
      const u16* kp_ = Kbb + (size_t)((KO) + n * 16 + li) * HDIM + g * 8;  \
      K0A[n] = *(const bf16x8*)(kp_);                                      \
      K1A[n] = *(const bf16x8*)(kp_ + 32);                                 \
    }                                                                      \
  } while (0)

#define ISSUE_V(KO)                                                        \
  do {                                                                     \
    _Pragma("unroll") for (int n = 0; n < 4; n++) {                        \
      const u16* vp_ = Vtb + (size_t)(n * 16 + li) * TSEQ + (KO) + g * 8;  \
      vf0[n] = *(const bf16x8*)(vp_);                                      \
      vf1[n] = *(const bf16x8*)(vp_ + 32);                                 \
    }                                                                      \
  } while (0)

#define COMPUTE_TILE(K0A, K1A, KO)                                         \
  do {                                                                     \
    f32x4 sA_[4], sB_[4];                                                  \
    __builtin_amdgcn_s_setprio(1);                                         \
    _Pragma("unroll") for (int n = 0; n < 4; n++) {                        \
      sA_[n] = (f32x4)0.f;                                                 \
      sA_[n] = __builtin_amdgcn_mfma_f32_16x16x32_bf16(K0A[n], qa0[0], sA_[n], 0, 0, 0); \
      sA_[n] = __builtin_amdgcn_mfma_f32_16x16x32_bf16(K1A[n], qa0[1], sA_[n], 0, 0, 0); \
      sB_[n] = (f32x4)0.f;                                                 \
      sB_[n] = __builtin_amdgcn_mfma_f32_16x16x32_bf16(K0A[n], qa1[0], sB_[n], 0, 0, 0); \
      sB_[n] = __builtin_amdgcn_mfma_f32_16x16x32_bf16(K1A[n], qa1[1], sB_[n], 0, 0, 0); \
    }                                                                      \
    __builtin_amdgcn_s_setprio(0);                                         \
    _Pragma("unroll") for (int n = 0; n < 4; n++) {                        \
      const int kb_ = (KO) + n * 16 + g * 4;                               \
      float p0_ = (kb_ + 0 <= qiL0) ? exp2f(sA_[n][0]) : 1.0f;             \
      float p1_ = (kb_ + 1 <= qiL0) ? exp2f(sA_[n][1]) : 1.0f;             \
      float p2_ = (kb_ + 2 <= qiL0) ? exp2f(sA_[n][2]) : 1.0f;             \
      float p3_ = (kb_ + 3 <= qiL0) ? exp2f(sA_[n][3]) : 1.0f;             \
      zaccA += (p0_ + p1_) + (p2_ + p3_);                                  \
      uint2 pk_ = make_uint2((unsigned)f2b(p0_) | ((unsigned)f2b(p1_) << 16), \
                             (unsigned)f2b(p2_) | ((unsigned)f2b(p3_) << 16)); \
      *(uint2*)(sppw + li * 144 + n * 32 + g * 8) = pk_;                   \
      float q0_ = (kb_ + 0 <= qiL1) ? exp2f(sB_[n][0]) : 1.0f;             \
      float q1_ = (kb_ + 1 <= qiL1) ? exp2f(sB_[n][1]) : 1.0f;             \
      float q2_ = (kb_ + 2 <= qiL1) ? exp2f(sB_[n][2]) : 1.0f;             \
      float q3_ = (kb_ + 3 <= qiL1) ? exp2f(sB_[n][3]) : 1.0f;             \
      zaccB += (q0_ + q1_) + (q2_ + q3_);                                  \
      uint2 qk_ = make_uint2((unsigned)f2b(q0_) | ((unsigned)f2b(q1_) << 16), \
                             (unsigned)f2b(q2_) | ((unsigned)f2b(q3_) << 16)); \
      *(uint2*)(sppw + (li + 16) * 144 + n * 32 + g * 8) = qk_;            \
    }                                                                      \
    asm volatile("s_waitcnt lgkmcnt(0)" ::: "memory");                     \
    __builtin_amdgcn_sched_barrier(0);                                     \
    const bf16x8 paA0_ = *(const bf16x8*)(sppw + li * 144 + g * 16);       \
    const bf16x8 paA1_ = *(const bf16x8*)(sppw + li * 144 + 64 + g * 16);  \
    const bf16x8 paB0_ = *(const bf16x8*)(sppw + (li + 16) * 144 + g * 16);\
    const bf16x8 paB1_ = *(const bf16x8*)(sppw + (li + 16) * 144 + 64 + g * 16); \
    __builtin_amdgcn_s_setprio(1);                                         \
    _Pragma("unroll") for (int nt = 0; nt < 4; nt++) {                     \
      oaccA[nt] = __builtin_amdgcn_mfma_f32_16x16x32_bf16(paA0_, vf0[nt], oaccA[nt], 0, 0, 0); \
      oaccA[nt] = __builtin_amdgcn_mfma_f32_16x16x32_bf16(paA1_, vf1[nt], oaccA[nt], 0, 0, 0); \
      oaccB[nt] = __builtin_amdgcn_mfma_f32_16x16x32_bf16(paB0_, vf0[nt], oaccB[nt], 0, 0, 0); \
      oaccB[nt] = __builtin_amdgcn_mfma_f32_16x16x32_bf16(paB1_, vf1[nt], oaccB[nt], 0, 0, 0); \
    }                                                                      \
    __builtin_amdgcn_s_setprio(0);                                         \
  } while (0)

__global__ __launch_bounds__(256, 2) void attn_mfma(
    const u16* __restrict__ Qb, const u16* __restrict__ Kb,
    const u16* __restrict__ Vt, const float* __restrict__ CSS,
    float* __restrict__ Out) {
  __shared__ __align__(16) u16 spp[4][32][72];  // per-wave P staging (bf16)
  __shared__ float spm[4][32][68];              // merge buffer

  const int tid = threadIdx.x;
  const int w = tid >> 6, l = tid & 63;
  const int g = l >> 4, li = l & 15;

  const int gb = blockIdx.x & 7;    // batch -> XCD pin (bid % 8 round-robin)
  const int j = blockIdx.x >> 3;    // 0..63
  const int gr = 63 - j;            // longest-first
  const int q0 = gr * 32;
  const int qiL0 = q0 + li;         // q-set A row
  const int qiL1 = q0 + 16 + li;    // q-set B row

  char* sppw = (char*)&spp[w][0][0];

  const size_t qbase0 = ((size_t)gb * TSEQ + q0 + li) * HDIM;
  bf16x8 qa0[2], qa1[2];
  qa0[0] = *(const bf16x8*)(Qb + qbase0 + g * 8);
  qa0[1] = *(const bf16x8*)(Qb + qbase0 + g * 8 + 32);
  qa1[0] = *(const bf16x8*)(Qb + qbase0 + 16 * HDIM + g * 8);
  qa1[1] = *(const bf16x8*)(Qb + qbase0 + 16 * HDIM + g * 8 + 32);

  float zaccA = 0.f, zaccB = 0.f;
  f32x4 oaccA[4], oaccB[4];
#pragma unroll
  for (int nt = 0; nt < 4; nt++) { oaccA[nt] = (f32x4)0.f; oaccB[nt] = (f32x4)0.f; }

  const int nt = gr / 2 + 1;  // tiles covering keys 0..q0+31
  const u16* Kbb = Kb + (size_t)gb * TSEQ * HDIM;
  const u16* Vtb = Vt + (size_t)gb * 64 * TSEQ;

  bf16x8 kA0[4], kA1[4], kB0[4], kB1[4], vf0[4], vf1[4];

  int kt = w;
  if (kt < nt) {
    ISSUE_K(kA0, kA1, kt * 64);
    while (true) {
      ISSUE_V(kt * 64);
      if (kt + 4 < nt) ISSUE_K(kB0, kB1, (kt + 4) * 64);
      __builtin_amdgcn_sched_barrier(0);
      COMPUTE_TILE(kA0, kA1, kt * 64);
      kt += 4;
      if (kt >= nt) break;
      ISSUE_V(kt * 64);
      if (kt + 4 < nt) ISSUE_K(kA0, kA1, (kt + 4) * 64);
      __builtin_amdgcn_sched_barrier(0);
      COMPUTE_TILE(kB0, kB1, kt * 64);
      kt += 4;
      if (kt >= nt) break;
    }
  }

  // Z: reduce over the 4 g-groups (lane bits 4,5)
  zaccA += __shfl_xor(zaccA, 16, 64);
  zaccA += __shfl_xor(zaccA, 32, 64);
  zaccB += __shfl_xor(zaccB, 16, 64);
  zaccB += __shfl_xor(zaccB, 32, 64);

  // publish partials into this wave's own spm region
#pragma unroll
  for (int n = 0; n < 4; n++) {
#pragma unroll
    for (int r = 0; r < 4; r++) {
      spm[w][g * 4 + r][n * 16 + li] = oaccA[n][r];
      spm[w][16 + g * 4 + r][n * 16 + li] = oaccB[n][r];
    }
  }
  if (l < 16) spm[w][l][64] = zaccA;
  else if (l < 32) spm[w][16 + (l & 15)][64] = zaccB;
  __syncthreads();

  // merge 4 wave-partials + tail correction + normalize; thread (w,l):
  // q rows {w*8+r, r=0..7}, h = l
  const float tailz = (float)(TSEQ - nt * 64);
  const float tailv = CSS[((size_t)gb * 33 + nt) * 64 + l];
#pragma unroll
  for (int r = 0; r < 8; r++) {
    const int q = w * 8 + r;
    const int qi = q0 + q;
    float a = ((spm[0][q][l] + spm[1][q][l]) + (spm[2][q][l] + spm[3][q][l]));
    float zz = ((spm[0][q][64] + spm[1][q][64]) + (spm[2][q][64] + spm[3][q][64]));
    zz += tailz;
    a += tailv;
    Out[((size_t)gb * TSEQ + qi) * HDIM + l] = a / zz;
  }
}

// ---------------------------------------------------------------------------
extern "C" void kernel_launch(void* const* d_in, const int* in_sizes, int n_in,
                              void* d_out, int out_size, void* d_ws, size_t ws_size,
                              hipStream_t stream) {
  const float* X  = (const float*)d_in[0];
  const float* Wq = (const float*)d_in[1];
  const float* bq = (const float*)d_in[2];
  const float* Wk = (const float*)d_in[3];
  const float* bk = (const float*)d_in[4];
  const float* Wv = (const float*)d_in[5];
  const float* bv = (const float*)d_in[6];
  float* out = (float*)d_out;

  // workspace (~6.9 MB)
  char* ws = (char*)d_ws;
  u16*   Qb  = (u16*)(ws);                   // 2 MB  bf16 [NROW][64] (pre-scaled)
  u16*   Kb  = (u16*)(ws + 2097152);         // 2 MB  bf16 [NROW][64]
  u16*   Vt  = (u16*)(ws + 4194304);         // 2 MB  bf16 [B][64][T]
  u16*   Wt  = (u16*)(ws + 6291456);         // 384 KB bf16 [192][1024]
  float* CSS = (float*)(ws + 6684672);       // 67.6 KB fp32 [B][33][64]

  wt_kernel<<<48, 256, 0, stream>>>(Wq, Wk, Wv, Wt);
  proj_mfma<<<(NROW / 32) * 3, 256, 0, stream>>>(X, Wt, bq, bk, bv, Qb, Kb, Vt);
  css_kernel<<<NBATCH, 1024, 0, stream>>>(Vt, CSS);
  attn_mfma<<<512, 256, 0, stream>>>(Qb, Kb, Vt, CSS, out);
}

// Round 17
// 69.881 us; speedup vs baseline: 1.1894x; 1.1894x over previous
//
#include <hip/hip_runtime.h>

// Problem constants
#define NBATCH 8
#define TSEQ 2048
#define EDIM 1024
#define HDIM 64
#define NROW (NBATCH * TSEQ)  // 16384

typedef unsigned short u16;
typedef __attribute__((ext_vector_type(8))) short bf16x8;   // 8 bf16 (4 VGPRs)
typedef __attribute__((ext_vector_type(8))) short short8;   // 16B load vehicle
typedef __attribute__((ext_vector_type(4))) float f32x4;

typedef unsigned int uint_as1 __attribute__((address_space(1)));
typedef unsigned int uint_as3 __attribute__((address_space(3)));

// fp32 -> bf16 round-to-nearest-even (bit pattern)
__device__ __forceinline__ u16 f2b(float x) {
  unsigned int u = __float_as_uint(x);
  unsigned int r = (u + 0x7fffu + ((u >> 16) & 1u)) >> 16;
  return (u16)r;
}
__device__ __forceinline__ float b2f(u16 h) {
  return __uint_as_float(((unsigned int)h) << 16);
}
// async global->LDS, 16 B per lane (dest = wave base + lane*16, linear)
__device__ __forceinline__ void gl16(const void* g, void* l) {
  __builtin_amdgcn_global_load_lds((const uint_as1*)g, (uint_as3*)l, 16, 0, 0);
}

// ---------------------------------------------------------------------------
// Kernel 0: W [1024][64] fp32 -> Wt [192][1024] bf16 (transposed), via LDS.
// ---------------------------------------------------------------------------
__global__ __launch_bounds__(256) void wt_kernel(
    const float* __restrict__ Wq, const float* __restrict__ Wk,
    const float* __restrict__ Wv, u16* __restrict__ Wt) {
  __shared__ float s[64][65];
  const int o = blockIdx.x >> 4, et = blockIdx.x & 15;
  const float* W = (o == 0) ? Wq : (o == 1) ? Wk : Wv;
  const int t = threadIdx.x;
  const int e0 = et * 64;
#pragma unroll
  for (int i = 0; i < 16; i++) {
    int e = i * 4 + (t >> 6), h = t & 63;
    s[e][h] = W[(size_t)(e0 + e) * HDIM + h];
  }
  __syncthreads();
#pragma unroll
  for (int j = 0; j < 16; j++) {
    int h = j * 4 + (t >> 6), e = t & 63;
    Wt[(size_t)(o * 64 + h) * EDIM + e0 + e] = f2b(s[e][h]);
  }
}

// ---------------------------------------------------------------------------
// Kernel 1: QKV projection — r9 version verbatim (best measured, ~34 us).
// 9 structural variants (r7-r16: serial, dbuf, counted-vmcnt, depth-3,
// 3 register-pipelines, W-stationary, o-split-TLP) all landed 33-49 us;
// duration invariant to sync depth, memory residency (warm=cold), and TLP
// -> walled for this technique set. 512 blocks (32 t) x 256 thr,
// counted vmcnt(8) + raw s_barrier double-buffer.
// ---------------------------------------------------------------------------
#define XBUF (32 * 256)    // 8 KB per buffer
#define WBUF (192 * 128)   // 24 KB per buffer

__global__ __launch_bounds__(256, 2) void proj_mfma(
    const float* __restrict__ X, const u16* __restrict__ Wt,
    const float* __restrict__ bq, const float* __restrict__ bk,
    const float* __restrict__ bv,
    u16* __restrict__ Qb, u16* __restrict__ Kb, u16* __restrict__ Vt) {
  __shared__ __align__(16) char sx[2 * XBUF];  // [buf][32 t][16 gran] fp32
  __shared__ __align__(16) char sw[2 * WBUF];  // [buf][192 h][8 gran] bf16

  const int tid = threadIdx.x;
  const int w = tid >> 6, l = tid & 63;
  const int g = l >> 4, li = l & 15;
  const long bt0 = (long)blockIdx.x * 32;

  const int xr = tid >> 4, xc = tid & 15;
  const float* xsrc0 = X + (bt0 + xr) * EDIM + ((xc ^ (xr & 7)) * 4);
  const float* xsrc1 = X + (bt0 + 16 + xr) * EDIM + ((xc ^ (xr & 7)) * 4);

  f32x4 acc[6];  // [mt][cs]
#pragma unroll
  for (int i = 0; i < 6; i++) acc[i] = (f32x4)0.f;

#define STAGE(BUF, E0)                                                       \
  do {                                                                       \
    gl16(xsrc0 + (E0), sx + (BUF)*XBUF + tid * 16);                          \
    gl16(xsrc1 + (E0), sx + (BUF)*XBUF + (tid + 256) * 16);                  \
    _Pragma("unroll") for (int j = 0; j < 6; j++) {                          \
      const int L = j * 256 + tid;                                           \
      const int r = L >> 3, c = L & 7;                                       \
      gl16(Wt + (size_t)r * EDIM + (E0) + ((c ^ (r & 7)) * 8),               \
           sw + (BUF)*WBUF + L * 16);                                        \
    }                                                                        \
  } while (0)

  STAGE(0, 0);
  asm volatile("s_waitcnt vmcnt(0)" ::: "memory");
  __builtin_amdgcn_sched_barrier(0);
  __builtin_amdgcn_s_barrier();
  __builtin_amdgcn_sched_barrier(0);

  for (int ks = 0; ks < 16; ks++) {
    const int buf = ks & 1;
    if (ks < 15) STAGE(buf ^ 1, (ks + 1) * 64);
    __builtin_amdgcn_sched_barrier(0);
    if (ks < 15) {
      asm volatile("s_waitcnt vmcnt(8)" ::: "memory");
    } else {
      asm volatile("s_waitcnt vmcnt(0)" ::: "memory");
    }
    __builtin_amdgcn_sched_barrier(0);
    __builtin_amdgcn_s_barrier();  // all waves' stage-k data in LDS
    __builtin_amdgcn_sched_barrier(0);

    const char* xb = sx + buf * XBUF;
    const char* wb = sw + buf * WBUF;
    bf16x8 bfr[2][2];
#pragma unroll
    for (int cs = 0; cs < 2; cs++) {
      const int row = cs * 16 + li;
#pragma unroll
      for (int kc = 0; kc < 2; kc++) {
        const int G0 = kc * 8 + g * 2;
        const float4 f0 = *(const float4*)(xb + row * 256 + ((G0 ^ (row & 7)) * 16));
        const float4 f1 = *(const float4*)(xb + row * 256 + (((G0 + 1) ^ (row & 7)) * 16));
        bfr[cs][kc] = (bf16x8){(short)f2b(f0.x), (short)f2b(f0.y),
                               (short)f2b(f0.z), (short)f2b(f0.w),
                               (short)f2b(f1.x), (short)f2b(f1.y),
                               (short)f2b(f1.z), (short)f2b(f1.w)};
      }
    }
#pragma unroll
    for (int mt = 0; mt < 3; mt++) {
      const int row = w * 48 + mt * 16 + li;
#pragma unroll
      for (int kc = 0; kc < 2; kc++) {
        const int G = kc * 4 + g;
        const bf16x8 af = *(const bf16x8*)(wb + row * 128 + ((G ^ (row & 7)) * 16));
        acc[mt * 2 + 0] = __builtin_amdgcn_mfma_f32_16x16x32_bf16(
            af, bfr[0][kc], acc[mt * 2 + 0], 0, 0, 0);
        acc[mt * 2 + 1] = __builtin_amdgcn_mfma_f32_16x16x32_bf16(
            af, bfr[1][kc], acc[mt * 2 + 1], 0, 0, 0);
      }
    }
    __builtin_amdgcn_sched_barrier(0);
    __builtin_amdgcn_s_barrier();  // reads of buf done before next overwrite
    __builtin_amdgcn_sched_barrier(0);
  }
#undef STAGE

  const float qscale = 0.18033688011112042f;  // 0.125 * log2(e)
#pragma unroll
  for (int cs = 0; cs < 2; cs++) {
    const long tg = bt0 + cs * 16 + li;
    const int b = (int)(tg >> 11), tl = (int)(tg & 2047);
#pragma unroll
    for (int mt = 0; mt < 3; mt++) {
      const int n0 = w * 48 + mt * 16 + g * 4;
      const int o = n0 >> 6;
      const int h0 = n0 & 63;
      const float* bias = (o == 0) ? bq : (o == 1) ? bk : bv;
      const float4 bb = *(const float4*)&bias[h0];
      const f32x4 a = acc[mt * 2 + cs];
      float v0 = a.x + bb.x, v1 = a.y + bb.y;
      float v2 = a.z + bb.z, v3 = a.w + bb.w;
      if (o == 0) {
        v0 *= qscale; v1 *= qscale; v2 *= qscale; v3 *= qscale;
        uint2 pk = make_uint2((unsigned)f2b(v0) | ((unsigned)f2b(v1) << 16),
                              (unsigned)f2b(v2) | ((unsigned)f2b(v3) << 16));
        *(uint2*)&Qb[tg * HDIM + h0] = pk;
      } else if (o == 1) {
        uint2 pk = make_uint2((unsigned)f2b(v0) | ((unsigned)f2b(v1) << 16),
                              (unsigned)f2b(v2) | ((unsigned)f2b(v3) << 16));
        *(uint2*)&Kb[tg * HDIM + h0] = pk;
      } else {
        Vt[(size_t)(b * 64 + h0 + 0) * TSEQ + tl] = f2b(v0);
        Vt[(size_t)(b * 64 + h0 + 1) * TSEQ + tl] = f2b(v1);
        Vt[(size_t)(b * 64 + h0 + 2) * TSEQ + tl] = f2b(v2);
        Vt[(size_t)(b * 64 + h0 + 3) * TSEQ + tl] = f2b(v3);
      }
    }
  }
}

// ---------------------------------------------------------------------------
// Kernel 2: per-64-chunk V sums + suffix table (single kernel).
// CSS[b][c][h] = sum_{k >= c*64} V[b][k][h], c = 0..32 (CSS[32] = 0).
// ---------------------------------------------------------------------------
__global__ __launch_bounds__(1024) void css_kernel(const u16* __restrict__ Vt,
                                                   float* __restrict__ CSS) {
  __shared__ float cs[32][64];
  const int b = blockIdx.x;
  const int t = threadIdx.x;
  const int h = t & 63, cg = t >> 6;
  const u16* vp = Vt + ((size_t)b * 64 + h) * TSEQ + cg * 128;
  float s0 = 0.f, s1 = 0.f;
#pragma unroll
  for (int i = 0; i < 8; i++) {
    const short8 a = *(const short8*)(vp + i * 8);
    s0 += b2f((u16)a[0]) + b2f((u16)a[1]) + b2f((u16)a[2]) + b2f((u16)a[3]) +
          b2f((u16)a[4]) + b2f((u16)a[5]) + b2f((u16)a[6]) + b2f((u16)a[7]);
  }
#pragma unroll
  for (int i = 8; i < 16; i++) {
    const short8 a = *(const short8*)(vp + i * 8);
    s1 += b2f((u16)a[0]) + b2f((u16)a[1]) + b2f((u16)a[2]) + b2f((u16)a[3]) +
          b2f((u16)a[4]) + b2f((u16)a[5]) + b2f((u16)a[6]) + b2f((u16)a[7]);
  }
  cs[cg * 2 + 0][h] = s0;
  cs[cg * 2 + 1][h] = s1;
  __syncthreads();
  if (t < 64) {
    float S = 0.f;
    CSS[((size_t)b * 33 + 32) * 64 + t] = 0.f;
    for (int c = 31; c >= 0; c--) {
      S += cs[c][t];
      CSS[((size_t)b * 33 + c) * 64 + t] = S;
    }
  }
}

// ---------------------------------------------------------------------------
// Kernel 3: MFMA attention: swapped QK^T, 32 q-rows/block, s_setprio around
// MFMA clusters (best measured attn variant).
// ---------------------------------------------------------------------------
#define ISSUE_K(K0A, K1A, KO)                                              \
  do {                                                                     \
    _Pragma("unroll") for (int n = 0; n < 4; n++) {                        \
      const u16* kp_ = Kbb + (size_t)((KO) + n * 16 + li) * HDIM + g * 8;  \
      K0A[n] = *(const bf16x8*)(kp_);                                      \
      K1A[n] = *(const bf16x8*)(kp_ + 32);                                 \
    }                                                                      \
  } while (0)

#define ISSUE_V(KO)                                                        \
  do {                                                                     \
    _Pragma("unroll") for (int n = 0; n < 4; n++) {                        \
      const u16* vp_ = Vtb + (size_t)(n * 16 + li) * TSEQ + (KO) + g * 8;  \
      vf0[n] = *(const bf16x8*)(vp_);                                      \
      vf1[n] = *(const bf16x8*)(vp_ + 32);                                 \
    }                                                                      \
  } while (0)

#define COMPUTE_TILE(K0A, K1A, KO)                                         \
  do {                                                                     \
    f32x4 sA_[4], sB_[4];                                                  \
    __builtin_amdgcn_s_setprio(1);                                         \
    _Pragma("unroll") for (int n = 0; n < 4; n++) {                        \
      sA_[n] = (f32x4)0.f;                                                 \
      sA_[n] = __builtin_amdgcn_mfma_f32_16x16x32_bf16(K0A[n], qa0[0], sA_[n], 0, 0, 0); \
      sA_[n] = __builtin_amdgcn_mfma_f32_16x16x32_bf16(K1A[n], qa0[1], sA_[n], 0, 0, 0); \
      sB_[n] = (f32x4)0.f;                                                 \
      sB_[n] = __builtin_amdgcn_mfma_f32_16x16x32_bf16(K0A[n], qa1[0], sB_[n], 0, 0, 0); \
      sB_[n] = __builtin_amdgcn_mfma_f32_16x16x32_bf16(K1A[n], qa1[1], sB_[n], 0, 0, 0); \
    }                                                                      \
    __builtin_amdgcn_s_setprio(0);                                         \
    _Pragma("unroll") for (int n = 0; n < 4; n++) {                        \
      const int kb_ = (KO) + n * 16 + g * 4;                               \
      float p0_ = (kb_ + 0 <= qiL0) ? exp2f(sA_[n][0]) : 1.0f;             \
      float p1_ = (kb_ + 1 <= qiL0) ? exp2f(sA_[n][1]) : 1.0f;             \
      float p2_ = (kb_ + 2 <= qiL0) ? exp2f(sA_[n][2]) : 1.0f;             \
      float p3_ = (kb_ + 3 <= qiL0) ? exp2f(sA_[n][3]) : 1.0f;             \
      zaccA += (p0_ + p1_) + (p2_ + p3_);                                  \
      uint2 pk_ = make_uint2((unsigned)f2b(p0_) | ((unsigned)f2b(p1_) << 16), \
                             (unsigned)f2b(p2_) | ((unsigned)f2b(p3_) << 16)); \
      *(uint2*)(sppw + li * 144 + n * 32 + g * 8) = pk_;                   \
      float q0_ = (kb_ + 0 <= qiL1) ? exp2f(sB_[n][0]) : 1.0f;             \
      float q1_ = (kb_ + 1 <= qiL1) ? exp2f(sB_[n][1]) : 1.0f;             \
      float q2_ = (kb_ + 2 <= qiL1) ? exp2f(sB_[n][2]) : 1.0f;             \
      float q3_ = (kb_ + 3 <= qiL1) ? exp2f(sB_[n][3]) : 1.0f;             \
      zaccB += (q0_ + q1_) + (q2_ + q3_);                                  \
      uint2 qk_ = make_uint2((unsigned)f2b(q0_) | ((unsigned)f2b(q1_) << 16), \
                             (unsigned)f2b(q2_) | ((unsigned)f2b(q3_) << 16)); \
      *(uint2*)(sppw + (li + 16) * 144 + n * 32 + g * 8) = qk_;            \
    }                                                                      \
    asm volatile("s_waitcnt lgkmcnt(0)" ::: "memory");                     \
    __builtin_amdgcn_sched_barrier(0);                                     \
    const bf16x8 paA0_ = *(const bf16x8*)(sppw + li * 144 + g * 16);       \
    const bf16x8 paA1_ = *(const bf16x8*)(sppw + li * 144 + 64 + g * 16);  \
    const bf16x8 paB0_ = *(const bf16x8*)(sppw + (li + 16) * 144 + g * 16);\
    const bf16x8 paB1_ = *(const bf16x8*)(sppw + (li + 16) * 144 + 64 + g * 16); \
    __builtin_amdgcn_s_setprio(1);                                         \
    _Pragma("unroll") for (int nt = 0; nt < 4; nt++) {                     \
      oaccA[nt] = __builtin_amdgcn_mfma_f32_16x16x32_bf16(paA0_, vf0[nt], oaccA[nt], 0, 0, 0); \
      oaccA[nt] = __builtin_amdgcn_mfma_f32_16x16x32_bf16(paA1_, vf1[nt], oaccA[nt], 0, 0, 0); \
      oaccB[nt] = __builtin_amdgcn_mfma_f32_16x16x32_bf16(paB0_, vf0[nt], oaccB[nt], 0, 0, 0); \
      oaccB[nt] = __builtin_amdgcn_mfma_f32_16x16x32_bf16(paB1_, vf1[nt], oaccB[nt], 0, 0, 0); \
    }                                                                      \
    __builtin_amdgcn_s_setprio(0);                                         \
  } while (0)

__global__ __launch_bounds__(256, 2) void attn_mfma(
    const u16* __restrict__ Qb, const u16* __restrict__ Kb,
    const u16* __restrict__ Vt, const float* __restrict__ CSS,
    float* __restrict__ Out) {
  __shared__ __align__(16) u16 spp[4][32][72];  // per-wave P staging (bf16)
  __shared__ float spm[4][32][68];              // merge buffer

  const int tid = threadIdx.x;
  const int w = tid >> 6, l = tid & 63;
  const int g = l >> 4, li = l & 15;

  const int gb = blockIdx.x & 7;    // batch -> XCD pin (bid % 8 round-robin)
  const int j = blockIdx.x >> 3;    // 0..63
  const int gr = 63 - j;            // longest-first
  const int q0 = gr * 32;
  const int qiL0 = q0 + li;         // q-set A row
  const int qiL1 = q0 + 16 + li;    // q-set B row

  char* sppw = (char*)&spp[w][0][0];

  const size_t qbase0 = ((size_t)gb * TSEQ + q0 + li) * HDIM;
  bf16x8 qa0[2], qa1[2];
  qa0[0] = *(const bf16x8*)(Qb + qbase0 + g * 8);
  qa0[1] = *(const bf16x8*)(Qb + qbase0 + g * 8 + 32);
  qa1[0] = *(const bf16x8*)(Qb + qbase0 + 16 * HDIM + g * 8);
  qa1[1] = *(const bf16x8*)(Qb + qbase0 + 16 * HDIM + g * 8 + 32);

  float zaccA = 0.f, zaccB = 0.f;
  f32x4 oaccA[4], oaccB[4];
#pragma unroll
  for (int nt = 0; nt < 4; nt++) { oaccA[nt] = (f32x4)0.f; oaccB[nt] = (f32x4)0.f; }

  const int nt = gr / 2 + 1;  // tiles covering keys 0..q0+31
  const u16* Kbb = Kb + (size_t)gb * TSEQ * HDIM;
  const u16* Vtb = Vt + (size_t)gb * 64 * TSEQ;

  bf16x8 kA0[4], kA1[4], kB0[4], kB1[4], vf0[4], vf1[4];

  int kt = w;
  if (kt < nt) {
    ISSUE_K(kA0, kA1, kt * 64);
    while (true) {
      ISSUE_V(kt * 64);
      if (kt + 4 < nt) ISSUE_K(kB0, kB1, (kt + 4) * 64);
      __builtin_amdgcn_sched_barrier(0);
      COMPUTE_TILE(kA0, kA1, kt * 64);
      kt += 4;
      if (kt >= nt) break;
      ISSUE_V(kt * 64);
      if (kt + 4 < nt) ISSUE_K(kA0, kA1, (kt + 4) * 64);
      __builtin_amdgcn_sched_barrier(0);
      COMPUTE_TILE(kB0, kB1, kt * 64);
      kt += 4;
      if (kt >= nt) break;
    }
  }

  // Z: reduce over the 4 g-groups (lane bits 4,5)
  zaccA += __shfl_xor(zaccA, 16, 64);
  zaccA += __shfl_xor(zaccA, 32, 64);
  zaccB += __shfl_xor(zaccB, 16, 64);
  zaccB += __shfl_xor(zaccB, 32, 64);

  // publish partials into this wave's own spm region
#pragma unroll
  for (int n = 0; n < 4; n++) {
#pragma unroll
    for (int r = 0; r < 4; r++) {
      spm[w][g * 4 + r][n * 16 + li] = oaccA[n][r];
      spm[w][16 + g * 4 + r][n * 16 + li] = oaccB[n][r];
    }
  }
  if (l < 16) spm[w][l][64] = zaccA;
  else if (l < 32) spm[w][16 + (l & 15)][64] = zaccB;
  __syncthreads();

  // merge 4 wave-partials + tail correction + normalize; thread (w,l):
  // q rows {w*8+r, r=0..7}, h = l
  const float tailz = (float)(TSEQ - nt * 64);
  const float tailv = CSS[((size_t)gb * 33 + nt) * 64 + l];
#pragma unroll
  for (int r = 0; r < 8; r++) {
    const int q = w * 8 + r;
    const int qi = q0 + q;
    float a = ((spm[0][q][l] + spm[1][q][l]) + (spm[2][q][l] + spm[3][q][l]));
    float zz = ((spm[0][q][64] + spm[1][q][64]) + (spm[2][q][64] + spm[3][q][64]));
    zz += tailz;
    a += tailv;
    Out[((size_t)gb * TSEQ + qi) * HDIM + l] = a / zz;
  }
}

// ---------------------------------------------------------------------------
extern "C" void kernel_launch(void* const* d_in, const int* in_sizes, int n_in,
                              void* d_out, int out_size, void* d_ws, size_t ws_size,
                              hipStream_t stream) {
  const float* X  = (const float*)d_in[0];
  const float* Wq = (const float*)d_in[1];
  const float* bq = (const float*)d_in[2];
  const float* Wk = (const float*)d_in[3];
  const float* bk = (const float*)d_in[4];
  const float* Wv = (const float*)d_in[5];
  const float* bv = (const float*)d_in[6];
  float* out = (float*)d_out;

  // workspace (~6.9 MB)
  char* ws = (char*)d_ws;
  u16*   Qb  = (u16*)(ws);                   // 2 MB  bf16 [NROW][64] (pre-scaled)
  u16*   Kb  = (u16*)(ws + 2097152);         // 2 MB  bf16 [NROW][64]
  u16*   Vt  = (u16*)(ws + 4194304);         // 2 MB  bf16 [B][64][T]
  u16*   Wt  = (u16*)(ws + 6291456);         // 384 KB bf16 [192][1024]
  float* CSS = (float*)(ws + 6684672);       // 67.6 KB fp32 [B][33][64]

  wt_kernel<<<48, 256, 0, stream>>>(Wq, Wk, Wv, Wt);
  proj_mfma<<<NROW / 32, 256, 0, stream>>>(X, Wt, bq, bk, bv, Qb, Kb, Vt);
  css_kernel<<<NBATCH, 1024, 0, stream>>>(Vt, CSS);
  attn_mfma<<<512, 256, 0, stream>>>(Qb, Kb, Vt, CSS, out);
}

// Round 18
// 61.310 us; speedup vs baseline: 1.3557x; 1.1398x over previous
//
#include <hip/hip_runtime.h>

// Problem constants
#define NBATCH 8
#define TSEQ 2048
#define EDIM 1024
#define HDIM 64
#define NROW (NBATCH * TSEQ)  // 16384

typedef unsigned short u16;
typedef __attribute__((ext_vector_type(8))) short bf16x8;   // 8 bf16 (4 VGPRs)
typedef __attribute__((ext_vector_type(8))) short short8;   // 16B load vehicle
typedef __attribute__((ext_vector_type(4))) float f32x4;

typedef unsigned int uint_as1 __attribute__((address_space(1)));
typedef unsigned int uint_as3 __attribute__((address_space(3)));

// fp32 -> bf16 round-to-nearest-even (bit pattern)
__device__ __forceinline__ u16 f2b(float x) {
  unsigned int u = __float_as_uint(x);
  unsigned int r = (u + 0x7fffu + ((u >> 16) & 1u)) >> 16;
  return (u16)r;
}
__device__ __forceinline__ float b2f(u16 h) {
  return __uint_as_float(((unsigned int)h) << 16);
}
// async global->LDS, 16 B per lane (dest = wave base + lane*16, linear)
__device__ __forceinline__ void gl16(const void* g, void* l) {
  __builtin_amdgcn_global_load_lds((const uint_as1*)g, (uint_as3*)l, 16, 0, 0);
}

// ---------------------------------------------------------------------------
// Kernel 0: W [1024][64] fp32 -> Wt [192][1024] bf16 (transposed), via LDS.
// Also zeroes CS (runs every call, before proj's atomics -> replay-safe).
// ---------------------------------------------------------------------------
__global__ __launch_bounds__(256) void wt_kernel(
    const float* __restrict__ Wq, const float* __restrict__ Wk,
    const float* __restrict__ Wv, u16* __restrict__ Wt,
    float* __restrict__ CS) {
  __shared__ float s[64][65];
  const int o = blockIdx.x >> 4, et = blockIdx.x & 15;
  const float* W = (o == 0) ? Wq : (o == 1) ? Wk : Wv;
  const int t = threadIdx.x;
  const int e0 = et * 64;
  // zero the chunk-sum table (8*32*64 = 16384 floats)
  for (int i = blockIdx.x * 256 + t; i < NBATCH * 32 * 64; i += 48 * 256)
    CS[i] = 0.f;
#pragma unroll
  for (int i = 0; i < 16; i++) {
    int e = i * 4 + (t >> 6), h = t & 63;
    s[e][h] = W[(size_t)(e0 + e) * HDIM + h];
  }
  __syncthreads();
#pragma unroll
  for (int j = 0; j < 16; j++) {
    int h = j * 4 + (t >> 6), e = t & 63;
    Wt[(size_t)(o * 64 + h) * EDIM + e0 + e] = f2b(s[e][h]);
  }
}

// ---------------------------------------------------------------------------
// Kernel 1: QKV projection — r9 pipeline verbatim (best measured, ~34 us;
// 9 structural variants all landed 33-49 us -> walled for this technique
// set). 512 blocks (32 t) x 256 thr, counted vmcnt(8) + raw s_barrier dbuf.
// NEW (r18): epilogue accumulates this block's V chunk-partials (sum over
// its 32 t rows) and atomicAdds into CS[b][c][h] — replaces css_kernel.
// ---------------------------------------------------------------------------
#define XBUF (32 * 256)    // 8 KB per buffer
#define WBUF (192 * 128)   // 24 KB per buffer

__global__ __launch_bounds__(256, 2) void proj_mfma(
    const float* __restrict__ X, const u16* __restrict__ Wt,
    const float* __restrict__ bq, const float* __restrict__ bk,
    const float* __restrict__ bv,
    u16* __restrict__ Qb, u16* __restrict__ Kb, u16* __restrict__ Vt,
    float* __restrict__ CS) {
  __shared__ __align__(16) char sx[2 * XBUF];  // [buf][32 t][16 gran] fp32
  __shared__ __align__(16) char sw[2 * WBUF];  // [buf][192 h][8 gran] bf16

  const int tid = threadIdx.x;
  const int w = tid >> 6, l = tid & 63;
  const int g = l >> 4, li = l & 15;
  const long bt0 = (long)blockIdx.x * 32;

  const int xr = tid >> 4, xc = tid & 15;
  const float* xsrc0 = X + (bt0 + xr) * EDIM + ((xc ^ (xr & 7)) * 4);
  const float* xsrc1 = X + (bt0 + 16 + xr) * EDIM + ((xc ^ (xr & 7)) * 4);

  f32x4 acc[6];  // [mt][cs]
#pragma unroll
  for (int i = 0; i < 6; i++) acc[i] = (f32x4)0.f;

#define STAGE(BUF, E0)                                                       \
  do {                                                                       \
    gl16(xsrc0 + (E0), sx + (BUF)*XBUF + tid * 16);                          \
    gl16(xsrc1 + (E0), sx + (BUF)*XBUF + (tid + 256) * 16);                  \
    _Pragma("unroll") for (int j = 0; j < 6; j++) {                          \
      const int L = j * 256 + tid;                                           \
      const int r = L >> 3, c = L & 7;                                       \
      gl16(Wt + (size_t)r * EDIM + (E0) + ((c ^ (r & 7)) * 8),               \
           sw + (BUF)*WBUF + L * 16);                                        \
    }                                                                        \
  } while (0)

  STAGE(0, 0);
  asm volatile("s_waitcnt vmcnt(0)" ::: "memory");
  __builtin_amdgcn_sched_barrier(0);
  __builtin_amdgcn_s_barrier();
  __builtin_amdgcn_sched_barrier(0);

  for (int ks = 0; ks < 16; ks++) {
    const int buf = ks & 1;
    if (ks < 15) STAGE(buf ^ 1, (ks + 1) * 64);
    __builtin_amdgcn_sched_barrier(0);
    if (ks < 15) {
      asm volatile("s_waitcnt vmcnt(8)" ::: "memory");
    } else {
      asm volatile("s_waitcnt vmcnt(0)" ::: "memory");
    }
    __builtin_amdgcn_sched_barrier(0);
    __builtin_amdgcn_s_barrier();  // all waves' stage-k data in LDS
    __builtin_amdgcn_sched_barrier(0);

    const char* xb = sx + buf * XBUF;
    const char* wb = sw + buf * WBUF;
    bf16x8 bfr[2][2];
#pragma unroll
    for (int cs = 0; cs < 2; cs++) {
      const int row = cs * 16 + li;
#pragma unroll
      for (int kc = 0; kc < 2; kc++) {
        const int G0 = kc * 8 + g * 2;
        const float4 f0 = *(const float4*)(xb + row * 256 + ((G0 ^ (row & 7)) * 16));
        const float4 f1 = *(const float4*)(xb + row * 256 + (((G0 + 1) ^ (row & 7)) * 16));
        bfr[cs][kc] = (bf16x8){(short)f2b(f0.x), (short)f2b(f0.y),
                               (short)f2b(f0.z), (short)f2b(f0.w),
                               (short)f2b(f1.x), (short)f2b(f1.y),
                               (short)f2b(f1.z), (short)f2b(f1.w)};
      }
    }
#pragma unroll
    for (int mt = 0; mt < 3; mt++) {
      const int row = w * 48 + mt * 16 + li;
#pragma unroll
      for (int kc = 0; kc < 2; kc++) {
        const int G = kc * 4 + g;
        const bf16x8 af = *(const bf16x8*)(wb + row * 128 + ((G ^ (row & 7)) * 16));
        acc[mt * 2 + 0] = __builtin_amdgcn_mfma_f32_16x16x32_bf16(
            af, bfr[0][kc], acc[mt * 2 + 0], 0, 0, 0);
        acc[mt * 2 + 1] = __builtin_amdgcn_mfma_f32_16x16x32_bf16(
            af, bfr[1][kc], acc[mt * 2 + 1], 0, 0, 0);
      }
    }
    __builtin_amdgcn_sched_barrier(0);
    __builtin_amdgcn_s_barrier();  // reads of buf done before next overwrite
    __builtin_amdgcn_sched_barrier(0);
  }
#undef STAGE

  const float qscale = 0.18033688011112042f;  // 0.125 * log2(e)
  float vsum[3][4];
#pragma unroll
  for (int mt = 0; mt < 3; mt++)
#pragma unroll
    for (int jj = 0; jj < 4; jj++) vsum[mt][jj] = 0.f;

#pragma unroll
  for (int cs = 0; cs < 2; cs++) {
    const long tg = bt0 + cs * 16 + li;
    const int b = (int)(tg >> 11), tl = (int)(tg & 2047);
#pragma unroll
    for (int mt = 0; mt < 3; mt++) {
      const int n0 = w * 48 + mt * 16 + g * 4;
      const int o = n0 >> 6;
      const int h0 = n0 & 63;
      const float* bias = (o == 0) ? bq : (o == 1) ? bk : bv;
      const float4 bb = *(const float4*)&bias[h0];
      const f32x4 a = acc[mt * 2 + cs];
      float v0 = a.x + bb.x, v1 = a.y + bb.y;
      float v2 = a.z + bb.z, v3 = a.w + bb.w;
      if (o == 0) {
        v0 *= qscale; v1 *= qscale; v2 *= qscale; v3 *= qscale;
        uint2 pk = make_uint2((unsigned)f2b(v0) | ((unsigned)f2b(v1) << 16),
                              (unsigned)f2b(v2) | ((unsigned)f2b(v3) << 16));
        *(uint2*)&Qb[tg * HDIM + h0] = pk;
      } else if (o == 1) {
        uint2 pk = make_uint2((unsigned)f2b(v0) | ((unsigned)f2b(v1) << 16),
                              (unsigned)f2b(v2) | ((unsigned)f2b(v3) << 16));
        *(uint2*)&Kb[tg * HDIM + h0] = pk;
      } else {
        Vt[(size_t)(b * 64 + h0 + 0) * TSEQ + tl] = f2b(v0);
        Vt[(size_t)(b * 64 + h0 + 1) * TSEQ + tl] = f2b(v1);
        Vt[(size_t)(b * 64 + h0 + 2) * TSEQ + tl] = f2b(v2);
        Vt[(size_t)(b * 64 + h0 + 3) * TSEQ + tl] = f2b(v3);
        vsum[mt][0] += v0; vsum[mt][1] += v1;
        vsum[mt][2] += v2; vsum[mt][3] += v3;
      }
    }
  }

  // chunk-partial publish: reduce each V-tile's sums over the 16 li lanes,
  // then one lane atomicAdds into CS[b][c][h0..h0+3].
  {
    const int b = (int)(bt0 >> 11);
    const int c = (int)((bt0 & 2047) >> 6);
    float* csrow = CS + ((size_t)(b * 32 + c) << 6);
#pragma unroll
    for (int mt = 0; mt < 3; mt++) {
      const int n0 = w * 48 + mt * 16 + g * 4;
      if (n0 >= 128) {  // V tile
        float s0 = vsum[mt][0], s1 = vsum[mt][1];
        float s2 = vsum[mt][2], s3 = vsum[mt][3];
#pragma unroll
        for (int d = 1; d < 16; d <<= 1) {
          s0 += __shfl_xor(s0, d, 64);
          s1 += __shfl_xor(s1, d, 64);
          s2 += __shfl_xor(s2, d, 64);
          s3 += __shfl_xor(s3, d, 64);
        }
        if (li == 0) {
          const int h0 = n0 & 63;
          atomicAdd(&csrow[h0 + 0], s0);
          atomicAdd(&csrow[h0 + 1], s1);
          atomicAdd(&csrow[h0 + 2], s2);
          atomicAdd(&csrow[h0 + 3], s3);
        }
      }
    }
  }
}

// ---------------------------------------------------------------------------
// Kernel 2: MFMA attention: swapped QK^T, 32 q-rows/block, s_setprio around
// MFMA clusters (best measured attn variant). NEW (r18): tail suffix-sum is
// computed on the fly from CS (<=31 L2-hot loads once per block) instead of
// a precomputed CSS table — css_kernel is gone.
// ---------------------------------------------------------------------------
#define ISSUE_K(K0A, K1A, KO)                                              \
  do {                                                                     \
    _Pragma("unroll") for (int n = 0; n < 4; n++) {                        \
      const u16* kp_ = Kbb + (size_t)((KO) + n * 16 + li) * HDIM + g * 8;  \
      K0A[n] = *(const bf16x8*)(kp_);                                      \
      K1A[n] = *(const bf16x8*)(kp_ + 32);                                 \
    }                                                                      \
  } while (0)

#define ISSUE_V(KO)                                                        \
  do {                                                                     \
    _Pragma("unroll") for (int n = 0; n < 4; n++) {                        \
      const u16* vp_ = Vtb + (size_t)(n * 16 + li) * TSEQ + (KO) + g * 8;  \
      vf0[n] = *(const bf16x8*)(vp_);                                      \
      vf1[n] = *(const bf16x8*)(vp_ + 32);                                 \
    }                                                                      \
  } while (0)

#define COMPUTE_TILE(K0A, K1A, KO)                                         \
  do {                                                                     \
    f32x4 sA_[4], sB_[4];                                                  \
    __builtin_amdgcn_s_setprio(1);                                         \
    _Pragma("unroll") for (int n = 0; n < 4; n++) {                        \
      sA_[n] = (f32x4)0.f;                                                 \
      sA_[n] = __builtin_amdgcn_mfma_f32_16x16x32_bf16(K0A[n], qa0[0], sA_[n], 0, 0, 0); \
      sA_[n] = __builtin_amdgcn_mfma_f32_16x16x32_bf16(K1A[n], qa0[1], sA_[n], 0, 0, 0); \
      sB_[n] = (f32x4)0.f;                                                 \
      sB_[n] = __builtin_amdgcn_mfma_f32_16x16x32_bf16(K0A[n], qa1[0], sB_[n], 0, 0, 0); \
      sB_[n] = __builtin_amdgcn_mfma_f32_16x16x32_bf16(K1A[n], qa1[1], sB_[n], 0, 0, 0); \
    }                                                                      \
    __builtin_amdgcn_s_setprio(0);                                         \
    _Pragma("unroll") for (int n = 0; n < 4; n++) {                        \
      const int kb_ = (KO) + n * 16 + g * 4;                               \
      float p0_ = (kb_ + 0 <= qiL0) ? exp2f(sA_[n][0]) : 1.0f;             \
      float p1_ = (kb_ + 1 <= qiL0) ? exp2f(sA_[n][1]) : 1.0f;             \
      float p2_ = (kb_ + 2 <= qiL0) ? exp2f(sA_[n][2]) : 1.0f;             \
      float p3_ = (kb_ + 3 <= qiL0) ? exp2f(sA_[n][3]) : 1.0f;             \
      zaccA += (p0_ + p1_) + (p2_ + p3_);                                  \
      uint2 pk_ = make_uint2((unsigned)f2b(p0_) | ((unsigned)f2b(p1_) << 16), \
                             (unsigned)f2b(p2_) | ((unsigned)f2b(p3_) << 16)); \
      *(uint2*)(sppw + li * 144 + n * 32 + g * 8) = pk_;                   \
      float q0_ = (kb_ + 0 <= qiL1) ? exp2f(sB_[n][0]) : 1.0f;             \
      float q1_ = (kb_ + 1 <= qiL1) ? exp2f(sB_[n][1]) : 1.0f;             \
      float q2_ = (kb_ + 2 <= qiL1) ? exp2f(sB_[n][2]) : 1.0f;             \
      float q3_ = (kb_ + 3 <= qiL1) ? exp2f(sB_[n][3]) : 1.0f;             \
      zaccB += (q0_ + q1_) + (q2_ + q3_);                                  \
      uint2 qk_ = make_uint2((unsigned)f2b(q0_) | ((unsigned)f2b(q1_) << 16), \
                             (unsigned)f2b(q2_) | ((unsigned)f2b(q3_) << 16)); \
      *(uint2*)(sppw + (li + 16) * 144 + n * 32 + g * 8) = qk_;            \
    }                                                                      \
    asm volatile("s_waitcnt lgkmcnt(0)" ::: "memory");                     \
    __builtin_amdgcn_sched_barrier(0);                                     \
    const bf16x8 paA0_ = *(const bf16x8*)(sppw + li * 144 + g * 16);       \
    const bf16x8 paA1_ = *(const bf16x8*)(sppw + li * 144 + 64 + g * 16);  \
    const bf16x8 paB0_ = *(const bf16x8*)(sppw + (li + 16) * 144 + g * 16);\
    const bf16x8 paB1_ = *(const bf16x8*)(sppw + (li + 16) * 144 + 64 + g * 16); \
    __builtin_amdgcn_s_setprio(1);                                         \
    _Pragma("unroll") for (int nt = 0; nt < 4; nt++) {                     \
      oaccA[nt] = __builtin_amdgcn_mfma_f32_16x16x32_bf16(paA0_, vf0[nt], oaccA[nt], 0, 0, 0); \
      oaccA[nt] = __builtin_amdgcn_mfma_f32_16x16x32_bf16(paA1_, vf1[nt], oaccA[nt], 0, 0, 0); \
      oaccB[nt] = __builtin_amdgcn_mfma_f32_16x16x32_bf16(paB0_, vf0[nt], oaccB[nt], 0, 0, 0); \
      oaccB[nt] = __builtin_amdgcn_mfma_f32_16x16x32_bf16(paB1_, vf1[nt], oaccB[nt], 0, 0, 0); \
    }                                                                      \
    __builtin_amdgcn_s_setprio(0);                                         \
  } while (0)

__global__ __launch_bounds__(256, 2) void attn_mfma(
    const u16* __restrict__ Qb, const u16* __restrict__ Kb,
    const u16* __restrict__ Vt, const float* __restrict__ CS,
    float* __restrict__ Out) {
  __shared__ __align__(16) u16 spp[4][32][72];  // per-wave P staging (bf16)
  __shared__ float spm[4][32][68];              // merge buffer

  const int tid = threadIdx.x;
  const int w = tid >> 6, l = tid & 63;
  const int g = l >> 4, li = l & 15;

  const int gb = blockIdx.x & 7;    // batch -> XCD pin (bid % 8 round-robin)
  const int j = blockIdx.x >> 3;    // 0..63
  const int gr = 63 - j;            // longest-first
  const int q0 = gr * 32;
  const int qiL0 = q0 + li;         // q-set A row
  const int qiL1 = q0 + 16 + li;    // q-set B row

  char* sppw = (char*)&spp[w][0][0];

  const size_t qbase0 = ((size_t)gb * TSEQ + q0 + li) * HDIM;
  bf16x8 qa0[2], qa1[2];
  qa0[0] = *(const bf16x8*)(Qb + qbase0 + g * 8);
  qa0[1] = *(const bf16x8*)(Qb + qbase0 + g * 8 + 32);
  qa1[0] = *(const bf16x8*)(Qb + qbase0 + 16 * HDIM + g * 8);
  qa1[1] = *(const bf16x8*)(Qb + qbase0 + 16 * HDIM + g * 8 + 32);

  float zaccA = 0.f, zaccB = 0.f;
  f32x4 oaccA[4], oaccB[4];
#pragma unroll
  for (int nt = 0; nt < 4; nt++) { oaccA[nt] = (f32x4)0.f; oaccB[nt] = (f32x4)0.f; }

  const int nt = gr / 2 + 1;  // tiles covering keys 0..q0+31
  const u16* Kbb = Kb + (size_t)gb * TSEQ * HDIM;
  const u16* Vtb = Vt + (size_t)gb * 64 * TSEQ;

  bf16x8 kA0[4], kA1[4], kB0[4], kB1[4], vf0[4], vf1[4];

  int kt = w;
  if (kt < nt) {
    ISSUE_K(kA0, kA1, kt * 64);
    while (true) {
      ISSUE_V(kt * 64);
      if (kt + 4 < nt) ISSUE_K(kB0, kB1, (kt + 4) * 64);
      __builtin_amdgcn_sched_barrier(0);
      COMPUTE_TILE(kA0, kA1, kt * 64);
      kt += 4;
      if (kt >= nt) break;
      ISSUE_V(kt * 64);
      if (kt + 4 < nt) ISSUE_K(kA0, kA1, (kt + 4) * 64);
      __builtin_amdgcn_sched_barrier(0);
      COMPUTE_TILE(kB0, kB1, kt * 64);
      kt += 4;
      if (kt >= nt) break;
    }
  }

  // Z: reduce over the 4 g-groups (lane bits 4,5)
  zaccA += __shfl_xor(zaccA, 16, 64);
  zaccA += __shfl_xor(zaccA, 32, 64);
  zaccB += __shfl_xor(zaccB, 16, 64);
  zaccB += __shfl_xor(zaccB, 32, 64);

  // publish partials into this wave's own spm region
#pragma unroll
  for (int n = 0; n < 4; n++) {
#pragma unroll
    for (int r = 0; r < 4; r++) {
      spm[w][g * 4 + r][n * 16 + li] = oaccA[n][r];
      spm[w][16 + g * 4 + r][n * 16 + li] = oaccB[n][r];
    }
  }
  if (l < 16) spm[w][l][64] = zaccA;
  else if (l < 32) spm[w][16 + (l & 15)][64] = zaccB;
  __syncthreads();

  // merge 4 wave-partials + tail correction + normalize; thread (w,l):
  // q rows {w*8+r, r=0..7}, h = l
  const float tailz = (float)(TSEQ - nt * 64);
  float tailv = 0.f;
  for (int c = nt; c < 32; c++) tailv += CS[((size_t)(gb * 32 + c) << 6) + l];
#pragma unroll
  for (int r = 0; r < 8; r++) {
    const int q = w * 8 + r;
    const int qi = q0 + q;
    float a = ((spm[0][q][l] + spm[1][q][l]) + (spm[2][q][l] + spm[3][q][l]));
    float zz = ((spm[0][q][64] + spm[1][q][64]) + (spm[2][q][64] + spm[3][q][64]));
    zz += tailz;
    a += tailv;
    Out[((size_t)gb * TSEQ + qi) * HDIM + l] = a / zz;
  }
}

// ---------------------------------------------------------------------------
extern "C" void kernel_launch(void* const* d_in, const int* in_sizes, int n_in,
                              void* d_out, int out_size, void* d_ws, size_t ws_size,
                              hipStream_t stream) {
  const float* X  = (const float*)d_in[0];
  const float* Wq = (const float*)d_in[1];
  const float* bq = (const float*)d_in[2];
  const float* Wk = (const float*)d_in[3];
  const float* bk = (const float*)d_in[4];
  const float* Wv = (const float*)d_in[5];
  const float* bv = (const float*)d_in[6];
  float* out = (float*)d_out;

  // workspace (~6.8 MB)
  char* ws = (char*)d_ws;
  u16*   Qb  = (u16*)(ws);                   // 2 MB  bf16 [NROW][64] (pre-scaled)
  u16*   Kb  = (u16*)(ws + 2097152);         // 2 MB  bf16 [NROW][64]
  u16*   Vt  = (u16*)(ws + 4194304);         // 2 MB  bf16 [B][64][T]
  u16*   Wt  = (u16*)(ws + 6291456);         // 384 KB bf16 [192][1024]
  float* CS  = (float*)(ws + 6684672);       // 64 KB fp32 [B][32][64] chunk sums

  wt_kernel<<<48, 256, 0, stream>>>(Wq, Wk, Wv, Wt, CS);
  proj_mfma<<<NROW / 32, 256, 0, stream>>>(X, Wt, bq, bk, bv, Qb, Kb, Vt, CS);
  attn_mfma<<<512, 256, 0, stream>>>(Qb, Kb, Vt, CS, out);
}